// Round 11
// baseline (95.888 us; speedup 1.0000x reference)
//
#include <hip/hip_runtime.h>

#define HID 1024
#define NH 16
#define HD 64
#define BB 2
#define LL 2048
#define GC 143   // number of global-summary columns
#define GP 192   // padded global columns (3 tiles of 64)
#define AMT_PER_B 2240  // 192 global slots + 16 windows * 128 local slots

typedef __attribute__((ext_vector_type(8))) __bf16 bf16x8;
typedef __attribute__((ext_vector_type(4))) float f32x4;
typedef __attribute__((ext_vector_type(4))) int i32x4;
typedef __attribute__((ext_vector_type(2))) unsigned long long u64x2;

__device__ __forceinline__ void gload_lds16(const void* g, void* l) {
  __builtin_amdgcn_global_load_lds((const __attribute__((address_space(1))) void*)g,
                                   (__attribute__((address_space(3))) void*)l, 16, 0, 0);
}

__device__ __forceinline__ unsigned int cvtpk(float lo, float hi) {
  unsigned int r;
  asm("v_cvt_pk_bf16_f32 %0, %1, %2" : "=v"(r) : "v"(lo), "v"(hi));
  return r;
}

// V^T A-fragment under the permuted formal-k: two 8B LDS reads (swizzled granules)
__device__ __forceinline__ bf16x8 vfrag(const char* vbase, int r, int gA, int gB,
                                        int half) {
  unsigned long long lo =
      *(const unsigned long long*)(vbase + r * 128 + ((gA ^ (r & 7)) << 4) + half);
  unsigned long long hi =
      *(const unsigned long long*)(vbase + r * 128 + ((gB ^ (r & 7)) << 4) + half);
  u64x2 u;
  u[0] = lo;
  u[1] = hi;
  return __builtin_bit_cast(bf16x8, u);
}

// ------- kernel 0: fused prep (cvt_hs | cvt_wt | zero+setup | amt table) -------
__global__ __launch_bounds__(256) void prep_kernel(
    const float* __restrict__ hs, __bf16* __restrict__ hsb,
    const float* __restrict__ Wq, const float* __restrict__ Wk,
    const float* __restrict__ Wv, __bf16* __restrict__ wtb,
    const float* __restrict__ amask, unsigned int* __restrict__ zbase,
    float* __restrict__ amt) {
  int bx = blockIdx.x;
  int t = threadIdx.x;
  if (bx < 2048) {
    // ---- hidden_states fp32 -> bf16 ----
    int i = bx * 256 + t;
    const float4* src = (const float4*)hs;
    float4 a = src[2 * i], b = src[2 * i + 1];
    bf16x8 v;
    v[0] = (__bf16)a.x; v[1] = (__bf16)a.y; v[2] = (__bf16)a.z; v[3] = (__bf16)a.w;
    v[4] = (__bf16)b.x; v[5] = (__bf16)b.y; v[6] = (__bf16)b.z; v[7] = (__bf16)b.w;
    ((bf16x8*)hsb)[i] = v;
  } else if (bx < 2048 + 768) {
    // ---- W [k][n] fp32 -> Wt [n][k] bf16 ----
    int z3 = bx - 2048;
    int kt = z3 & 15, nt = (z3 >> 4) & 15, z = z3 >> 8;
    const float* w = (z == 0) ? Wq : (z == 1) ? Wk : Wv;
    __bf16* dst = wtb + (size_t)z * HID * HID;
    __shared__ __bf16 tile[64][66];
    int cr = t & 63, rr = t >> 6;
#pragma unroll
    for (int it = 0; it < 16; it++) {
      int r = it * 4 + rr;
      tile[cr][r] = (__bf16)w[(size_t)(kt * 64 + r) * HID + nt * 64 + cr];
    }
    __syncthreads();
#pragma unroll
    for (int it = 0; it < 16; it++) {
      int r = it * 4 + rr;
      dst[(size_t)(nt * 64 + r) * HID + kt * 64 + cr] = tile[r][cr];
    }
  } else if (bx < 2048 + 768 + 1536) {
    // ---- zero compact K/V buffers ----
    int i = (bx - 2816) * 256 + t;  // 1536 blocks -> 393216 dwords
    zbase[i] = 0u;
  } else {
    // ---- combined additive softmax table: clip(s) + amt = ready for exp ----
    int idx = (bx - 4352) * 256 + t;
    if (idx < BB * AMT_PER_B) {
      int b = idx / AMT_PER_B, r = idx % AMT_PER_B;
      float val;
      if (r < GP) {
        int k = r / 9, j = r - 9 * k;
        val = (r < GC) ? (amask[b * LL + 120 + 128 * k + j] - 20.f) : -1e5f;
      } else {
        int r2 = r - GP;
        int w = r2 >> 7, off = r2 & 127;
        bool gcol = (off >= 120) || (off == 0 && w != 0);
        val = gcol ? -1e5f : (amask[b * LL + w * 128 + off] - 20.f);
      }
      amt[idx] = val;
    }
  }
}

// ------- kernel 1: QKV GEMM, 256x256 tile, BK=64, 8 waves (2Mx4N), phased -------
// Double-buffered LDS; staging for K-tile t+1 issued during t's phases 1-2 into
// the OTHER buffer (race-free); raw s_barrier per phase (no vmcnt drain);
// boundary s_waitcnt vmcnt(0) is free because all loads are >=2 phases old.
__global__ __launch_bounds__(512, 2) void qkv_gemm_kernel(
    const __bf16* __restrict__ hsb, const __bf16* __restrict__ wtb,
    const float* __restrict__ bq, const float* __restrict__ bk,
    const float* __restrict__ bv, __bf16* __restrict__ qb,
    __bf16* __restrict__ kkb, __bf16* __restrict__ vtb,
    __bf16* __restrict__ kgb, __bf16* __restrict__ vgb) {
  int nt = blockIdx.x, mt = blockIdx.y, which = blockIdx.z;
  const __bf16* wt = wtb + (size_t)which * HID * HID;
  const float* bias = (which == 0) ? bq : (which == 1) ? bk : bv;

  __shared__ __bf16 Ab[2][256 * 64];
  __shared__ __bf16 Bb[2][256 * 64];

  int tid = threadIdx.x;
  int wave = tid >> 6, lane = tid & 63;
  int wm = wave >> 2, wn = wave & 3;  // 2 M-waves x 4 N-waves
  int lrow = lane & 15, lgr = lane >> 4;

  // staging geometry: load i covers rows i*64 + wave*8 + (lane>>3)
  int srow_base = wave * 8 + (lane >> 3);
  int sg = lane & 7;

#define STAGE_A(KT, I)                                                        \
  do {                                                                        \
    int r_ = (I)*64 + srow_base;                                              \
    int gs_ = (sg ^ (r_ & 7)) * 8;                                            \
    gload_lds16(hsb + (size_t)(mt * 256 + r_) * HID + (KT)*64 + gs_,          \
                &Ab[(KT)&1][((I)*64 + wave * 8) * 64]);                       \
  } while (0)
#define STAGE_B(KT, I)                                                        \
  do {                                                                        \
    int r_ = (I)*64 + srow_base;                                              \
    int gs_ = (sg ^ (r_ & 7)) * 8;                                            \
    gload_lds16(wt + (size_t)(nt * 256 + r_) * HID + (KT)*64 + gs_,           \
                &Bb[(KT)&1][((I)*64 + wave * 8) * 64]);                       \
  } while (0)

  f32x4 acc[8][4];
#pragma unroll
  for (int i = 0; i < 8; i++)
#pragma unroll
    for (int j = 0; j < 4; j++) acc[i][j] = f32x4{0.f, 0.f, 0.f, 0.f};

  // prologue: stage K-tile 0, wait, barrier
#pragma unroll
  for (int i = 0; i < 4; i++) {
    STAGE_A(0, i);
    STAGE_B(0, i);
  }
  asm volatile("s_waitcnt vmcnt(0)" ::: "memory");
  __builtin_amdgcn_s_barrier();

  for (int t = 0; t < 16; t++) {
    const char* Ap = (const char*)&Ab[t & 1][0];
    const char* Bp = (const char*)&Bb[t & 1][0];

    // phase-1 ds: all B-frags (held across the K-tile) + A-frags 0,1
    bf16x8 bfr[4][2];
#pragma unroll
    for (int n = 0; n < 4; n++) {
      int row = wn * 64 + n * 16 + lrow;
#pragma unroll
      for (int kf = 0; kf < 2; kf++)
        bfr[n][kf] = *(const bf16x8*)(Bp + row * 128 +
                                      ((kf * 64 + lgr * 16) ^ ((row & 7) << 4)));
    }

#pragma unroll
    for (int p = 0; p < 4; p++) {
      bf16x8 af[2][2];
#pragma unroll
      for (int j = 0; j < 2; j++) {
        int row = wm * 128 + (2 * p + j) * 16 + lrow;
#pragma unroll
        for (int kf = 0; kf < 2; kf++)
          af[j][kf] = *(const bf16x8*)(Ap + row * 128 +
                                       ((kf * 64 + lgr * 16) ^ ((row & 7) << 4)));
      }
      // stage K-tile t+1 into the OTHER buffer (never read this K-tile)
      if (p == 0 && t < 15) {
        STAGE_A(t + 1, 1);
        STAGE_A(t + 1, 3);
      }
      if (p == 1 && t < 15) {
        STAGE_B(t + 1, 0);
        STAGE_B(t + 1, 1);
        STAGE_B(t + 1, 2);
        STAGE_B(t + 1, 3);
        STAGE_A(t + 1, 0);
        STAGE_A(t + 1, 2);
      }
      __builtin_amdgcn_s_barrier();
      __builtin_amdgcn_s_setprio(1);
#pragma unroll
      for (int j = 0; j < 2; j++)
#pragma unroll
        for (int n = 0; n < 4; n++) {
          acc[2 * p + j][n] = __builtin_amdgcn_mfma_f32_16x16x32_bf16(
              af[j][0], bfr[n][0], acc[2 * p + j][n], 0, 0, 0);
          acc[2 * p + j][n] = __builtin_amdgcn_mfma_f32_16x16x32_bf16(
              af[j][1], bfr[n][1], acc[2 * p + j][n], 0, 0, 0);
        }
      __builtin_amdgcn_s_setprio(0);
      __builtin_amdgcn_s_barrier();
    }

    // K-tile boundary: ensure t+1's stages landed everywhere (loads are >=2
    // phases old -> effectively no stall), then release the buffers.
    if (t < 15) {
      asm volatile("s_waitcnt vmcnt(0)" ::: "memory");
      __builtin_amdgcn_s_barrier();
    }
  }
#undef STAGE_A
#undef STAGE_B

  // epilogue: bias, (Q: x0.125), scatter to per-head layouts (+ global compacts)
#pragma unroll
  for (int nfr = 0; nfr < 4; nfr++) {
    int n = nt * 256 + wn * 64 + nfr * 16 + lrow;
    float bsv = bias[n];
    int hh = n >> 6, d = n & 63;
#pragma unroll
    for (int mfr = 0; mfr < 8; mfr++) {
#pragma unroll
      for (int reg = 0; reg < 4; reg++) {
        int m = mt * 256 + wm * 128 + mfr * 16 + lgr * 4 + reg;
        int bidx = m >> 11, l = m & 2047;
        float val = acc[mfr][nfr][reg] + bsv;
        int c7 = l & 127;
        bool isg = (c7 >= 120) || (c7 == 0 && l != 0);
        int cidx = (c7 >= 120) ? ((l >> 7) * 9 + (c7 - 120)) : (((l >> 7) - 1) * 9 + 8);
        if (which == 0) {
          val *= 0.125f;  // fold 1/sqrt(64) into Q (exact pow2)
          qb[((size_t)(bidx * NH + hh) * LL + l) * HD + d] = (__bf16)val;
        } else if (which == 1) {
          __bf16 bv16 = (__bf16)val;
          kkb[((size_t)(bidx * NH + hh) * LL + l) * HD + d] = bv16;
          if (isg) kgb[((size_t)(bidx * NH + hh) * GP + cidx) * HD + d] = bv16;
        } else {
          __bf16 bv16 = (__bf16)val;
          vtb[((size_t)(bidx * NH + hh) * HD + d) * LL + l] = bv16;
          if (isg) vgb[((size_t)(bidx * NH + hh) * HD + d) * GP + cidx] = bv16;
        }
      }
    }
  }
}

// ---- kernel 2: attention, transposed-output, 2 q-groups/wave, ZERO-shuffle PV.
// (unchanged from round 10)
__global__ __launch_bounds__(256, 4) void attn_kernel(
    const __bf16* __restrict__ qb, const __bf16* __restrict__ kkb,
    const __bf16* __restrict__ vtb, const __bf16* __restrict__ kgb,
    const __bf16* __restrict__ vgb, const float* __restrict__ amt,
    float* __restrict__ out) {
  __shared__ __bf16 kbuf[2][64 * 64];
  __shared__ __bf16 vbuf[2][64 * 64];

  int qt = blockIdx.x, hh = blockIdx.y, b = blockIdx.z;
  int tid = threadIdx.x, wave = tid >> 6, lane = tid & 63;
  int lrow = lane & 15, lgr = lane >> 4, g = lane & 7;

  const __bf16* qbh = qb + (size_t)(b * NH + hh) * LL * HD;
  const __bf16* kbh = kkb + (size_t)(b * NH + hh) * LL * HD;
  const __bf16* vth = vtb + (size_t)(b * NH + hh) * HD * LL;
  const __bf16* kgh = kgb + (size_t)(b * NH + hh) * GP * HD;
  const __bf16* vgh = vgb + (size_t)(b * NH + hh) * HD * GP;

  int shift = (qt == 16) ? 0 : 1;
  int qt2 = (qt == 16) ? 0 : qt;
  int W = qt2 * 128;
  const float* amt_b = amt + b * AMT_PER_B;
  const float* amt_l = amt_b + GP + qt2 * 128;

  int qrowA = qt2 * 128 + shift + wave * 32 + lrow;  // group A q-row
  int qrowB = qrowA + 16;                            // group B q-row
  int qldA = (qrowA > LL - 1) ? (LL - 1) : qrowA;
  int qldB = (qrowB > LL - 1) ? (LL - 1) : qrowB;
  bf16x8 qA0 = *(const bf16x8*)(qbh + (size_t)qldA * HD + lgr * 8);
  bf16x8 qA1 = *(const bf16x8*)(qbh + (size_t)qldA * HD + 32 + lgr * 8);
  bf16x8 qB0 = *(const bf16x8*)(qbh + (size_t)qldB * HD + lgr * 8);
  bf16x8 qB1 = *(const bf16x8*)(qbh + (size_t)qldB * HD + 32 + lgr * 8);

  // V-frag granule ids under sigma (fixed per lane)
  int g0 = lgr >> 1, half = (lgr & 1) * 8;

  float lA = 0.f, lB = 0.f;
  f32x4 oA[4], oB[4];
#pragma unroll
  for (int i = 0; i < 4; i++) {
    oA[i] = f32x4{0.f, 0.f, 0.f, 0.f};
    oB[i] = f32x4{0.f, 0.f, 0.f, 0.f};
  }

#define STAGE(IT, BI)                                                     \
  do {                                                                    \
    const __bf16 *ks_, *vs_;                                              \
    int vst_;                                                             \
    if ((IT) < 3) {                                                       \
      ks_ = kgh + (size_t)((IT)*64) * HD;                                 \
      vs_ = vgh + (IT)*64;                                                \
      vst_ = GP;                                                          \
    } else {                                                              \
      int cb_ = W + ((IT)-3) * 64;                                        \
      ks_ = kbh + (size_t)cb_ * HD;                                       \
      vs_ = vth + cb_;                                                    \
      vst_ = LL;                                                          \
    }                                                                     \
    _Pragma("unroll")                                                     \
    for (int i_ = 0; i_ < 2; i_++) {                                      \
      int r_ = (wave * 2 + i_) * 8 + (lane >> 3);                         \
      int gs_ = (g ^ (r_ & 7)) * 8;                                       \
      gload_lds16(ks_ + (size_t)r_ * HD + gs_, &kbuf[BI][(wave * 2 + i_) * 512]); \
      gload_lds16(vs_ + (size_t)r_ * vst_ + gs_, &vbuf[BI][(wave * 2 + i_) * 512]); \
    }                                                                     \
  } while (0)

  STAGE(0, 0);
  __syncthreads();

#pragma unroll
  for (int it = 0; it < 5; it++) {
    int cur = it & 1;
    if (it < 4) STAGE(it + 1, cur ^ 1);  // prefetch next (drained by barrier)

    const __bf16* k_lds = kbuf[cur];
    const char* v_ldsc = (const char*)vbuf[cur];

    // additive table: one broadcast f32x4 per nr (clip-add + kills, -M0 folded)
    const float* abase = (it < 3) ? (amt_b + it * 64) : (amt_l + (it - 3) * 64);
    f32x4 ad[4];
#pragma unroll
    for (int nr = 0; nr < 4; nr++)
      ad[nr] = *(const f32x4*)(abase + nr * 16 + lgr * 4);

    // S^T = K . Q^T for both q-groups (K fragments shared)
    f32x4 sA[4], sB[4];
    __builtin_amdgcn_s_setprio(1);
#pragma unroll
    for (int nr = 0; nr < 4; nr++) {
      int row = nr * 16 + lrow;
      bf16x8 kf0 = *(const bf16x8*)((const char*)k_lds + row * 128 +
                                    ((lgr * 16) ^ ((row & 7) << 4)));
      bf16x8 kf1 = *(const bf16x8*)((const char*)k_lds + row * 128 +
                                    ((64 + lgr * 16) ^ ((row & 7) << 4)));
      f32x4 zA = f32x4{0.f, 0.f, 0.f, 0.f};
      zA = __builtin_amdgcn_mfma_f32_16x16x32_bf16(kf0, qA0, zA, 0, 0, 0);
      zA = __builtin_amdgcn_mfma_f32_16x16x32_bf16(kf1, qA1, zA, 0, 0, 0);
      sA[nr] = zA;
      f32x4 zB = f32x4{0.f, 0.f, 0.f, 0.f};
      zB = __builtin_amdgcn_mfma_f32_16x16x32_bf16(kf0, qB0, zB, 0, 0, 0);
      zB = __builtin_amdgcn_mfma_f32_16x16x32_bf16(kf1, qB1, zB, 0, 0, 0);
      sB[nr] = zB;
    }
    __builtin_amdgcn_s_setprio(0);

    // p = exp(clip(s) + add); per-lane partial sums
#pragma unroll
    for (int nr = 0; nr < 4; nr++) {
#pragma unroll
      for (int reg = 0; reg < 4; reg++) {
        float vA = fminf(fmaxf(sA[nr][reg], -10000.f), 10000.f) + ad[nr][reg];
        float pA = __expf(vA);
        sA[nr][reg] = pA;
        lA += pA;
        float vB = fminf(fmaxf(sB[nr][reg], -10000.f), 10000.f) + ad[nr][reg];
        float pB = __expf(vB);
        sB[nr][reg] = pB;
        lB += pB;
      }
    }

    // pack P -> own-lane B-fragments (formal-k permutation; NO shuffle)
    i32x4 wA0, wA1, wB0, wB1;
    wA0[0] = (int)cvtpk(sA[0][0], sA[0][1]);
    wA0[1] = (int)cvtpk(sA[0][2], sA[0][3]);
    wA0[2] = (int)cvtpk(sA[1][0], sA[1][1]);
    wA0[3] = (int)cvtpk(sA[1][2], sA[1][3]);
    wA1[0] = (int)cvtpk(sA[2][0], sA[2][1]);
    wA1[1] = (int)cvtpk(sA[2][2], sA[2][3]);
    wA1[2] = (int)cvtpk(sA[3][0], sA[3][1]);
    wA1[3] = (int)cvtpk(sA[3][2], sA[3][3]);
    wB0[0] = (int)cvtpk(sB[0][0], sB[0][1]);
    wB0[1] = (int)cvtpk(sB[0][2], sB[0][3]);
    wB0[2] = (int)cvtpk(sB[1][0], sB[1][1]);
    wB0[3] = (int)cvtpk(sB[1][2], sB[1][3]);
    wB1[0] = (int)cvtpk(sB[2][0], sB[2][1]);
    wB1[1] = (int)cvtpk(sB[2][2], sB[2][3]);
    wB1[2] = (int)cvtpk(sB[3][0], sB[3][1]);
    wB1[3] = (int)cvtpk(sB[3][2], sB[3][3]);
    bf16x8 pbA0 = __builtin_bit_cast(bf16x8, wA0);
    bf16x8 pbA1 = __builtin_bit_cast(bf16x8, wA1);
    bf16x8 pbB0 = __builtin_bit_cast(bf16x8, wB0);
    bf16x8 pbB1 = __builtin_bit_cast(bf16x8, wB1);

    // O^T += V^T . P^T  (V A-frags under sigma, shared across groups)
    __builtin_amdgcn_s_setprio(1);
#pragma unroll
    for (int nd = 0; nd < 4; nd++) {
      int row = nd * 16 + lrow;  // d index
      bf16x8 va0 = vfrag(v_ldsc, row, g0, 2 + g0, half);
      bf16x8 va1 = vfrag(v_ldsc, row, 4 + g0, 6 + g0, half);
      oA[nd] = __builtin_amdgcn_mfma_f32_16x16x32_bf16(va0, pbA0, oA[nd], 0, 0, 0);
      oA[nd] = __builtin_amdgcn_mfma_f32_16x16x32_bf16(va1, pbA1, oA[nd], 0, 0, 0);
      oB[nd] = __builtin_amdgcn_mfma_f32_16x16x32_bf16(va0, pbB0, oB[nd], 0, 0, 0);
      oB[nd] = __builtin_amdgcn_mfma_f32_16x16x32_bf16(va1, pbB1, oB[nd], 0, 0, 0);
    }
    __builtin_amdgcn_s_setprio(0);
    if (it < 4) __syncthreads();  // buffer reuse + implicit vmcnt drain
  }
#undef STAGE

  // row-sums across the 4 lanes sharing each q
  lA += __shfl_xor(lA, 16);
  lA += __shfl_xor(lA, 32);
  lB += __shfl_xor(lB, 16);
  lB += __shfl_xor(lB, 32);
  float rlA = 1.f / lA, rlB = 1.f / lB;

  // O^T C-frag: lane reg r of quadrant nd = O[d = nd*16 + lgr*4 + r][q]
  if (qrowA < LL) {
    float* obase = out + ((size_t)b * LL + qrowA) * HID + hh * HD + lgr * 4;
#pragma unroll
    for (int nd = 0; nd < 4; nd++) {
      float4 ov;
      ov.x = oA[nd][0] * rlA;
      ov.y = oA[nd][1] * rlA;
      ov.z = oA[nd][2] * rlA;
      ov.w = oA[nd][3] * rlA;
      *(float4*)(obase + nd * 16) = ov;
    }
  }
  if (qrowB < LL) {
    float* obase = out + ((size_t)b * LL + qrowB) * HID + hh * HD + lgr * 4;
#pragma unroll
    for (int nd = 0; nd < 4; nd++) {
      float4 ov;
      ov.x = oB[nd][0] * rlB;
      ov.y = oB[nd][1] * rlB;
      ov.z = oB[nd][2] * rlB;
      ov.w = oB[nd][3] * rlB;
      *(float4*)(obase + nd * 16) = ov;
    }
  }
}

extern "C" void kernel_launch(void* const* d_in, const int* in_sizes, int n_in,
                              void* d_out, int out_size, void* d_ws, size_t ws_size,
                              hipStream_t stream) {
  (void)in_sizes; (void)n_in; (void)out_size; (void)ws_size;
  const float* hs = (const float*)d_in[0];
  const float* amask = (const float*)d_in[1];
  const float* Wq = (const float*)d_in[2];
  const float* bq = (const float*)d_in[3];
  const float* Wk = (const float*)d_in[4];
  const float* bk = (const float*)d_in[5];
  const float* Wv = (const float*)d_in[6];
  const float* bv = (const float*)d_in[7];
  float* out = (float*)d_out;

  char* ws = (char*)d_ws;
  // ws layout (bytes):
  // hsb 8388608 | wtb 6291456 | qb 8388608 | kb 8388608 | vtb 8388608
  // kgb 786432 | vgb 786432 | amt 17920
  __bf16* hsb = (__bf16*)(ws);
  __bf16* wtb = (__bf16*)(ws + 8388608);
  __bf16* qb  = (__bf16*)(ws + 14680064);
  __bf16* kb  = (__bf16*)(ws + 23068672);
  __bf16* vtb = (__bf16*)(ws + 31457280);
  __bf16* kgb = (__bf16*)(ws + 39845888);
  __bf16* vgb = (__bf16*)(ws + 40632320);
  float*  amt = (float*)(ws + 41418752);

  hipLaunchKernelGGL(prep_kernel, dim3(4370), dim3(256), 0, stream,
                     hs, hsb, Wq, Wk, Wv, wtb, amask, (unsigned int*)kgb, amt);
  hipLaunchKernelGGL(qkv_gemm_kernel, dim3(4, 16, 3), dim3(512), 0, stream,
                     hsb, wtb, bq, bk, bv, qb, kb, vtb, kgb, vgb);
  hipLaunchKernelGGL(attn_kernel, dim3(17, NH, BB), dim3(256), 0, stream,
                     qb, kb, vtb, kgb, vgb, amt, out);
}

// Round 12
// 92.136 us; speedup vs baseline: 1.0407x; 1.0407x over previous
//
#include <hip/hip_runtime.h>

#define HID 1024
#define NH 16
#define HD 64
#define BB 2
#define LL 2048
#define GC 143   // number of global-summary columns
#define GP 192   // padded global columns (3 tiles of 64)
#define AMT_PER_B 2240  // 192 global slots + 16 windows * 128 local slots

typedef __attribute__((ext_vector_type(8))) __bf16 bf16x8;
typedef __attribute__((ext_vector_type(4))) float f32x4;
typedef __attribute__((ext_vector_type(4))) int i32x4;
typedef __attribute__((ext_vector_type(2))) unsigned long long u64x2;

__device__ __forceinline__ void gload_lds16(const void* g, void* l) {
  __builtin_amdgcn_global_load_lds((const __attribute__((address_space(1))) void*)g,
                                   (__attribute__((address_space(3))) void*)l, 16, 0, 0);
}

__device__ __forceinline__ unsigned int cvtpk(float lo, float hi) {
  unsigned int r;
  asm("v_cvt_pk_bf16_f32 %0, %1, %2" : "=v"(r) : "v"(lo), "v"(hi));
  return r;
}

// V^T A-fragment under the permuted formal-k: two 8B LDS reads (swizzled granules)
__device__ __forceinline__ bf16x8 vfrag(const char* vbase, int r, int gA, int gB,
                                        int half) {
  unsigned long long lo =
      *(const unsigned long long*)(vbase + r * 128 + ((gA ^ (r & 7)) << 4) + half);
  unsigned long long hi =
      *(const unsigned long long*)(vbase + r * 128 + ((gB ^ (r & 7)) << 4) + half);
  u64x2 u;
  u[0] = lo;
  u[1] = hi;
  return __builtin_bit_cast(bf16x8, u);
}

// ------- kernel 0: fused prep (cvt_hs | cvt_wt | zero+setup | amt table) -------
__global__ __launch_bounds__(256) void prep_kernel(
    const float* __restrict__ hs, __bf16* __restrict__ hsb,
    const float* __restrict__ Wq, const float* __restrict__ Wk,
    const float* __restrict__ Wv, __bf16* __restrict__ wtb,
    const float* __restrict__ amask, unsigned int* __restrict__ zbase,
    float* __restrict__ amt) {
  int bx = blockIdx.x;
  int t = threadIdx.x;
  if (bx < 2048) {
    // ---- hidden_states fp32 -> bf16 ----
    int i = bx * 256 + t;
    const float4* src = (const float4*)hs;
    float4 a = src[2 * i], b = src[2 * i + 1];
    bf16x8 v;
    v[0] = (__bf16)a.x; v[1] = (__bf16)a.y; v[2] = (__bf16)a.z; v[3] = (__bf16)a.w;
    v[4] = (__bf16)b.x; v[5] = (__bf16)b.y; v[6] = (__bf16)b.z; v[7] = (__bf16)b.w;
    ((bf16x8*)hsb)[i] = v;
  } else if (bx < 2048 + 768) {
    // ---- W [k][n] fp32 -> Wt [n][k] bf16 ----
    int z3 = bx - 2048;
    int kt = z3 & 15, nt = (z3 >> 4) & 15, z = z3 >> 8;
    const float* w = (z == 0) ? Wq : (z == 1) ? Wk : Wv;
    __bf16* dst = wtb + (size_t)z * HID * HID;
    __shared__ __bf16 tile[64][66];
    int cr = t & 63, rr = t >> 6;
#pragma unroll
    for (int it = 0; it < 16; it++) {
      int r = it * 4 + rr;
      tile[cr][r] = (__bf16)w[(size_t)(kt * 64 + r) * HID + nt * 64 + cr];
    }
    __syncthreads();
#pragma unroll
    for (int it = 0; it < 16; it++) {
      int r = it * 4 + rr;
      dst[(size_t)(nt * 64 + r) * HID + kt * 64 + cr] = tile[r][cr];
    }
  } else if (bx < 2048 + 768 + 1536) {
    // ---- zero compact K/V buffers ----
    int i = (bx - 2816) * 256 + t;  // 1536 blocks -> 393216 dwords
    zbase[i] = 0u;
  } else {
    // ---- combined additive softmax table: clip(s) + amt = ready for exp ----
    int idx = (bx - 4352) * 256 + t;
    if (idx < BB * AMT_PER_B) {
      int b = idx / AMT_PER_B, r = idx % AMT_PER_B;
      float val;
      if (r < GP) {
        int k = r / 9, j = r - 9 * k;
        val = (r < GC) ? (amask[b * LL + 120 + 128 * k + j] - 20.f) : -1e5f;
      } else {
        int r2 = r - GP;
        int w = r2 >> 7, off = r2 & 127;
        bool gcol = (off >= 120) || (off == 0 && w != 0);
        val = gcol ? -1e5f : (amask[b * LL + w * 128 + off] - 20.f);
      }
      amt[idx] = val;
    }
  }
}

// ------- kernel 1: QKV GEMM, 256x256 tile, BK=64, 8 waves (2Mx4N) -------
// Catalog-minimum 2-phase: STAGE(next tile -> other buffer) issued FIRST,
// then full-tile ds_read+MFMA, then ONE vmcnt(0)+s_barrier per K-tile.
__global__ __launch_bounds__(512, 2) void qkv_gemm_kernel(
    const __bf16* __restrict__ hsb, const __bf16* __restrict__ wtb,
    const float* __restrict__ bq, const float* __restrict__ bk,
    const float* __restrict__ bv, __bf16* __restrict__ qb,
    __bf16* __restrict__ kkb, __bf16* __restrict__ vtb,
    __bf16* __restrict__ kgb, __bf16* __restrict__ vgb) {
  int nt = blockIdx.x, mt = blockIdx.y, which = blockIdx.z;
  const __bf16* wt = wtb + (size_t)which * HID * HID;
  const float* bias = (which == 0) ? bq : (which == 1) ? bk : bv;

  __shared__ __bf16 As[2][256 * 64];
  __shared__ __bf16 Bs[2][256 * 64];

  int tid = threadIdx.x;
  int wave = tid >> 6, lane = tid & 63;
  int wm = wave >> 2, wn = wave & 3;  // 2 M-waves x 4 N-waves
  int lrow = lane & 15, lgr = lane >> 4;
  int sg = tid & 7;

  // stage one full K-tile (A 256x64 + B 256x64): 8 gload_lds16 per thread
#define STG(KT, BUF)                                                          \
  do {                                                                        \
    _Pragma("unroll") for (int i_ = 0; i_ < 4; i_++) {                        \
      int r_ = i_ * 64 + (tid >> 3);                                          \
      int gs_ = (sg ^ (r_ & 7)) * 8;                                          \
      gload_lds16(hsb + (size_t)(mt * 256 + r_) * HID + (KT)*64 + gs_,        \
                  &As[BUF][(i_ * 64 + wave * 8) * 64]);                       \
      gload_lds16(wt + (size_t)(nt * 256 + r_) * HID + (KT)*64 + gs_,         \
                  &Bs[BUF][(i_ * 64 + wave * 8) * 64]);                       \
    }                                                                         \
  } while (0)

  f32x4 acc[8][4];
#pragma unroll
  for (int i = 0; i < 8; i++)
#pragma unroll
    for (int j = 0; j < 4; j++) acc[i][j] = f32x4{0.f, 0.f, 0.f, 0.f};

  STG(0, 0);
  asm volatile("s_waitcnt vmcnt(0)" ::: "memory");
  __builtin_amdgcn_s_barrier();

#pragma unroll 2
  for (int t = 0; t < 16; t++) {
    int cur = t & 1;
    const char* Ap = (const char*)&As[cur][0];
    const char* Bp = (const char*)&Bs[cur][0];
    if (t < 15) {
      if (cur) STG(t + 1, 0);
      else STG(t + 1, 1);
    }

    // B fragments for the whole tile (held across both m-halves)
    bf16x8 bfr[4][2];
#pragma unroll
    for (int n = 0; n < 4; n++) {
      int row = wn * 64 + n * 16 + lrow;
#pragma unroll
      for (int kf = 0; kf < 2; kf++)
        bfr[n][kf] = *(const bf16x8*)(Bp + row * 128 +
                                      ((kf * 64 + lgr * 16) ^ ((row & 7) << 4)));
    }

#pragma unroll
    for (int mh = 0; mh < 2; mh++) {
      bf16x8 af[4][2];
#pragma unroll
      for (int j = 0; j < 4; j++) {
        int row = wm * 128 + mh * 64 + j * 16 + lrow;
#pragma unroll
        for (int kf = 0; kf < 2; kf++)
          af[j][kf] = *(const bf16x8*)(Ap + row * 128 +
                                       ((kf * 64 + lgr * 16) ^ ((row & 7) << 4)));
      }
      __builtin_amdgcn_s_setprio(1);
#pragma unroll
      for (int j = 0; j < 4; j++)
#pragma unroll
        for (int n = 0; n < 4; n++) {
          acc[mh * 4 + j][n] = __builtin_amdgcn_mfma_f32_16x16x32_bf16(
              af[j][0], bfr[n][0], acc[mh * 4 + j][n], 0, 0, 0);
          acc[mh * 4 + j][n] = __builtin_amdgcn_mfma_f32_16x16x32_bf16(
              af[j][1], bfr[n][1], acc[mh * 4 + j][n], 0, 0, 0);
        }
      __builtin_amdgcn_s_setprio(0);
    }

    if (t < 15) {
      asm volatile("s_waitcnt vmcnt(0)" ::: "memory");
      __builtin_amdgcn_s_barrier();
    }
  }
#undef STG

  // epilogue: bias, (Q: x0.125), scatter to per-head layouts (+ global compacts)
#pragma unroll
  for (int nfr = 0; nfr < 4; nfr++) {
    int n = nt * 256 + wn * 64 + nfr * 16 + lrow;
    float bsv = bias[n];
    int hh = n >> 6, d = n & 63;
#pragma unroll
    for (int mfr = 0; mfr < 8; mfr++) {
#pragma unroll
      for (int reg = 0; reg < 4; reg++) {
        int m = mt * 256 + wm * 128 + mfr * 16 + lgr * 4 + reg;
        int bidx = m >> 11, l = m & 2047;
        float val = acc[mfr][nfr][reg] + bsv;
        int c7 = l & 127;
        bool isg = (c7 >= 120) || (c7 == 0 && l != 0);
        int cidx = (c7 >= 120) ? ((l >> 7) * 9 + (c7 - 120)) : (((l >> 7) - 1) * 9 + 8);
        if (which == 0) {
          val *= 0.125f;  // fold 1/sqrt(64) into Q (exact pow2)
          qb[((size_t)(bidx * NH + hh) * LL + l) * HD + d] = (__bf16)val;
        } else if (which == 1) {
          __bf16 bv16 = (__bf16)val;
          kkb[((size_t)(bidx * NH + hh) * LL + l) * HD + d] = bv16;
          if (isg) kgb[((size_t)(bidx * NH + hh) * GP + cidx) * HD + d] = bv16;
        } else {
          __bf16 bv16 = (__bf16)val;
          vtb[((size_t)(bidx * NH + hh) * HD + d) * LL + l] = bv16;
          if (isg) vgb[((size_t)(bidx * NH + hh) * HD + d) * GP + cidx] = bv16;
        }
      }
    }
  }
}

// ---- kernel 2: attention, transposed-output, 2 q-groups/wave, ZERO-shuffle PV.
// (unchanged from round 10)
__global__ __launch_bounds__(256, 4) void attn_kernel(
    const __bf16* __restrict__ qb, const __bf16* __restrict__ kkb,
    const __bf16* __restrict__ vtb, const __bf16* __restrict__ kgb,
    const __bf16* __restrict__ vgb, const float* __restrict__ amt,
    float* __restrict__ out) {
  __shared__ __bf16 kbuf[2][64 * 64];
  __shared__ __bf16 vbuf[2][64 * 64];

  int qt = blockIdx.x, hh = blockIdx.y, b = blockIdx.z;
  int tid = threadIdx.x, wave = tid >> 6, lane = tid & 63;
  int lrow = lane & 15, lgr = lane >> 4, g = lane & 7;

  const __bf16* qbh = qb + (size_t)(b * NH + hh) * LL * HD;
  const __bf16* kbh = kkb + (size_t)(b * NH + hh) * LL * HD;
  const __bf16* vth = vtb + (size_t)(b * NH + hh) * HD * LL;
  const __bf16* kgh = kgb + (size_t)(b * NH + hh) * GP * HD;
  const __bf16* vgh = vgb + (size_t)(b * NH + hh) * HD * GP;

  int shift = (qt == 16) ? 0 : 1;
  int qt2 = (qt == 16) ? 0 : qt;
  int W = qt2 * 128;
  const float* amt_b = amt + b * AMT_PER_B;
  const float* amt_l = amt_b + GP + qt2 * 128;

  int qrowA = qt2 * 128 + shift + wave * 32 + lrow;  // group A q-row
  int qrowB = qrowA + 16;                            // group B q-row
  int qldA = (qrowA > LL - 1) ? (LL - 1) : qrowA;
  int qldB = (qrowB > LL - 1) ? (LL - 1) : qrowB;
  bf16x8 qA0 = *(const bf16x8*)(qbh + (size_t)qldA * HD + lgr * 8);
  bf16x8 qA1 = *(const bf16x8*)(qbh + (size_t)qldA * HD + 32 + lgr * 8);
  bf16x8 qB0 = *(const bf16x8*)(qbh + (size_t)qldB * HD + lgr * 8);
  bf16x8 qB1 = *(const bf16x8*)(qbh + (size_t)qldB * HD + 32 + lgr * 8);

  // V-frag granule ids under sigma (fixed per lane)
  int g0 = lgr >> 1, half = (lgr & 1) * 8;

  float lA = 0.f, lB = 0.f;
  f32x4 oA[4], oB[4];
#pragma unroll
  for (int i = 0; i < 4; i++) {
    oA[i] = f32x4{0.f, 0.f, 0.f, 0.f};
    oB[i] = f32x4{0.f, 0.f, 0.f, 0.f};
  }

#define STAGE(IT, BI)                                                     \
  do {                                                                    \
    const __bf16 *ks_, *vs_;                                              \
    int vst_;                                                             \
    if ((IT) < 3) {                                                       \
      ks_ = kgh + (size_t)((IT)*64) * HD;                                 \
      vs_ = vgh + (IT)*64;                                                \
      vst_ = GP;                                                          \
    } else {                                                              \
      int cb_ = W + ((IT)-3) * 64;                                        \
      ks_ = kbh + (size_t)cb_ * HD;                                       \
      vs_ = vth + cb_;                                                    \
      vst_ = LL;                                                          \
    }                                                                     \
    _Pragma("unroll")                                                     \
    for (int i_ = 0; i_ < 2; i_++) {                                      \
      int r_ = (wave * 2 + i_) * 8 + (lane >> 3);                         \
      int gs_ = (g ^ (r_ & 7)) * 8;                                       \
      gload_lds16(ks_ + (size_t)r_ * HD + gs_, &kbuf[BI][(wave * 2 + i_) * 512]); \
      gload_lds16(vs_ + (size_t)r_ * vst_ + gs_, &vbuf[BI][(wave * 2 + i_) * 512]); \
    }                                                                     \
  } while (0)

  STAGE(0, 0);
  __syncthreads();

#pragma unroll
  for (int it = 0; it < 5; it++) {
    int cur = it & 1;
    if (it < 4) STAGE(it + 1, cur ^ 1);  // prefetch next (drained by barrier)

    const __bf16* k_lds = kbuf[cur];
    const char* v_ldsc = (const char*)vbuf[cur];

    // additive table: one broadcast f32x4 per nr (clip-add + kills, -M0 folded)
    const float* abase = (it < 3) ? (amt_b + it * 64) : (amt_l + (it - 3) * 64);
    f32x4 ad[4];
#pragma unroll
    for (int nr = 0; nr < 4; nr++)
      ad[nr] = *(const f32x4*)(abase + nr * 16 + lgr * 4);

    // S^T = K . Q^T for both q-groups (K fragments shared)
    f32x4 sA[4], sB[4];
    __builtin_amdgcn_s_setprio(1);
#pragma unroll
    for (int nr = 0; nr < 4; nr++) {
      int row = nr * 16 + lrow;
      bf16x8 kf0 = *(const bf16x8*)((const char*)k_lds + row * 128 +
                                    ((lgr * 16) ^ ((row & 7) << 4)));
      bf16x8 kf1 = *(const bf16x8*)((const char*)k_lds + row * 128 +
                                    ((64 + lgr * 16) ^ ((row & 7) << 4)));
      f32x4 zA = f32x4{0.f, 0.f, 0.f, 0.f};
      zA = __builtin_amdgcn_mfma_f32_16x16x32_bf16(kf0, qA0, zA, 0, 0, 0);
      zA = __builtin_amdgcn_mfma_f32_16x16x32_bf16(kf1, qA1, zA, 0, 0, 0);
      sA[nr] = zA;
      f32x4 zB = f32x4{0.f, 0.f, 0.f, 0.f};
      zB = __builtin_amdgcn_mfma_f32_16x16x32_bf16(kf0, qB0, zB, 0, 0, 0);
      zB = __builtin_amdgcn_mfma_f32_16x16x32_bf16(kf1, qB1, zB, 0, 0, 0);
      sB[nr] = zB;
    }
    __builtin_amdgcn_s_setprio(0);

    // p = exp(clip(s) + add); per-lane partial sums
#pragma unroll
    for (int nr = 0; nr < 4; nr++) {
#pragma unroll
      for (int reg = 0; reg < 4; reg++) {
        float vA = fminf(fmaxf(sA[nr][reg], -10000.f), 10000.f) + ad[nr][reg];
        float pA = __expf(vA);
        sA[nr][reg] = pA;
        lA += pA;
        float vB = fminf(fmaxf(sB[nr][reg], -10000.f), 10000.f) + ad[nr][reg];
        float pB = __expf(vB);
        sB[nr][reg] = pB;
        lB += pB;
      }
    }

    // pack P -> own-lane B-fragments (formal-k permutation; NO shuffle)
    i32x4 wA0, wA1, wB0, wB1;
    wA0[0] = (int)cvtpk(sA[0][0], sA[0][1]);
    wA0[1] = (int)cvtpk(sA[0][2], sA[0][3]);
    wA0[2] = (int)cvtpk(sA[1][0], sA[1][1]);
    wA0[3] = (int)cvtpk(sA[1][2], sA[1][3]);
    wA1[0] = (int)cvtpk(sA[2][0], sA[2][1]);
    wA1[1] = (int)cvtpk(sA[2][2], sA[2][3]);
    wA1[2] = (int)cvtpk(sA[3][0], sA[3][1]);
    wA1[3] = (int)cvtpk(sA[3][2], sA[3][3]);
    wB0[0] = (int)cvtpk(sB[0][0], sB[0][1]);
    wB0[1] = (int)cvtpk(sB[0][2], sB[0][3]);
    wB0[2] = (int)cvtpk(sB[1][0], sB[1][1]);
    wB0[3] = (int)cvtpk(sB[1][2], sB[1][3]);
    wB1[0] = (int)cvtpk(sB[2][0], sB[2][1]);
    wB1[1] = (int)cvtpk(sB[2][2], sB[2][3]);
    wB1[2] = (int)cvtpk(sB[3][0], sB[3][1]);
    wB1[3] = (int)cvtpk(sB[3][2], sB[3][3]);
    bf16x8 pbA0 = __builtin_bit_cast(bf16x8, wA0);
    bf16x8 pbA1 = __builtin_bit_cast(bf16x8, wA1);
    bf16x8 pbB0 = __builtin_bit_cast(bf16x8, wB0);
    bf16x8 pbB1 = __builtin_bit_cast(bf16x8, wB1);

    // O^T += V^T . P^T  (V A-frags under sigma, shared across groups)
    __builtin_amdgcn_s_setprio(1);
#pragma unroll
    for (int nd = 0; nd < 4; nd++) {
      int row = nd * 16 + lrow;  // d index
      bf16x8 va0 = vfrag(v_ldsc, row, g0, 2 + g0, half);
      bf16x8 va1 = vfrag(v_ldsc, row, 4 + g0, 6 + g0, half);
      oA[nd] = __builtin_amdgcn_mfma_f32_16x16x32_bf16(va0, pbA0, oA[nd], 0, 0, 0);
      oA[nd] = __builtin_amdgcn_mfma_f32_16x16x32_bf16(va1, pbA1, oA[nd], 0, 0, 0);
      oB[nd] = __builtin_amdgcn_mfma_f32_16x16x32_bf16(va0, pbB0, oB[nd], 0, 0, 0);
      oB[nd] = __builtin_amdgcn_mfma_f32_16x16x32_bf16(va1, pbB1, oB[nd], 0, 0, 0);
    }
    __builtin_amdgcn_s_setprio(0);
    if (it < 4) __syncthreads();  // buffer reuse + implicit vmcnt drain
  }
#undef STAGE

  // row-sums across the 4 lanes sharing each q
  lA += __shfl_xor(lA, 16);
  lA += __shfl_xor(lA, 32);
  lB += __shfl_xor(lB, 16);
  lB += __shfl_xor(lB, 32);
  float rlA = 1.f / lA, rlB = 1.f / lB;

  // O^T C-frag: lane reg r of quadrant nd = O[d = nd*16 + lgr*4 + r][q]
  if (qrowA < LL) {
    float* obase = out + ((size_t)b * LL + qrowA) * HID + hh * HD + lgr * 4;
#pragma unroll
    for (int nd = 0; nd < 4; nd++) {
      float4 ov;
      ov.x = oA[nd][0] * rlA;
      ov.y = oA[nd][1] * rlA;
      ov.z = oA[nd][2] * rlA;
      ov.w = oA[nd][3] * rlA;
      *(float4*)(obase + nd * 16) = ov;
    }
  }
  if (qrowB < LL) {
    float* obase = out + ((size_t)b * LL + qrowB) * HID + hh * HD + lgr * 4;
#pragma unroll
    for (int nd = 0; nd < 4; nd++) {
      float4 ov;
      ov.x = oB[nd][0] * rlB;
      ov.y = oB[nd][1] * rlB;
      ov.z = oB[nd][2] * rlB;
      ov.w = oB[nd][3] * rlB;
      *(float4*)(obase + nd * 16) = ov;
    }
  }
}

extern "C" void kernel_launch(void* const* d_in, const int* in_sizes, int n_in,
                              void* d_out, int out_size, void* d_ws, size_t ws_size,
                              hipStream_t stream) {
  (void)in_sizes; (void)n_in; (void)out_size; (void)ws_size;
  const float* hs = (const float*)d_in[0];
  const float* amask = (const float*)d_in[1];
  const float* Wq = (const float*)d_in[2];
  const float* bq = (const float*)d_in[3];
  const float* Wk = (const float*)d_in[4];
  const float* bk = (const float*)d_in[5];
  const float* Wv = (const float*)d_in[6];
  const float* bv = (const float*)d_in[7];
  float* out = (float*)d_out;

  char* ws = (char*)d_ws;
  // ws layout (bytes):
  // hsb 8388608 | wtb 6291456 | qb 8388608 | kb 8388608 | vtb 8388608
  // kgb 786432 | vgb 786432 | amt 17920
  __bf16* hsb = (__bf16*)(ws);
  __bf16* wtb = (__bf16*)(ws + 8388608);
  __bf16* qb  = (__bf16*)(ws + 14680064);
  __bf16* kb  = (__bf16*)(ws + 23068672);
  __bf16* vtb = (__bf16*)(ws + 31457280);
  __bf16* kgb = (__bf16*)(ws + 39845888);
  __bf16* vgb = (__bf16*)(ws + 40632320);
  float*  amt = (float*)(ws + 41418752);

  hipLaunchKernelGGL(prep_kernel, dim3(4370), dim3(256), 0, stream,
                     hs, hsb, Wq, Wk, Wv, wtb, amask, (unsigned int*)kgb, amt);
  hipLaunchKernelGGL(qkv_gemm_kernel, dim3(4, 16, 3), dim3(512), 0, stream,
                     hsb, wtb, bq, bk, bv, qb, kb, vtb, kgb, vgb);
  hipLaunchKernelGGL(attn_kernel, dim3(17, NH, BB), dim3(256), 0, stream,
                     qb, kb, vtb, kgb, vgb, amt, out);
}